// Round 2
// baseline (8366.338 us; speedup 1.0000x reference)
//
#include <hip/hip_runtime.h>
#include <math.h>

#pragma clang fp contract(off)

#define BB 64      // batch
#define N_IN 64
#define N_E 256
#define N_I 64
#define N_OUT 10

// r14 resubmit (previous round failed at the infra level: "MI355X container
// failed twice" -- no kernel verdict, no counters).
//
// SINGLE-WAVE redesign. One 64-lane wave per batch element; lane l owns
// E neurons {l, l+64, l+128, l+192}. Former wave-word g == __ballot(sE[g]).
// Consequences:
//  * The entire cross-wave reduction protocol (sPK/sKoT partials, tag write,
//    early probe, volatile poll fallback) is DELETED. E->I and E->O partials
//    are accumulated per-word in registers and combined ((p0+p1)+p2)+p3 --
//    the exact association order of the 4-wave kernel, so results stay
//    bit-identical.
//  * Wie staged TRANSPOSED in LDS as [j][l][g] so the per-lane 4-neuron kie
//    gather is ONE ds_read_b128 per spiking-I row (was 1 b32/row/wave).
//  * Gathers batch 8 rows per lgkm wait (add sequence incl. zero-row padding
//    identical to repeated batch-4 -> bit-exact; accumulators are >=0 so
//    +0.0f adds are exact).
//  * W_ee fallback merged into the main loop: kee[g]==0.0f when W_ee is all
//    zero, and ((ge+kin)+0.0f)*dA is bit-identical to (ge+kin)*dA.
// Everything else (LIF float sequences, delayed-O + drain, W0 two-deep input
// prefetch, merged Wei||W1 80-col rows, zero-row padding) copied verbatim
// from the verified 4.77 ms kernel.
__global__ __launch_bounds__(64, 1) void ping_kernel(
    const float* __restrict__ g_in,   // [T,64,64]
    const float* __restrict__ g_W0,   // [64,256]  clamp >=0 at use
    const float* __restrict__ g_W1,   // [256,10]  clamp >=0 at stage
    const float* __restrict__ g_Wee,  // [256,256]
    const float* __restrict__ g_Wei,  // [256,64]
    const float* __restrict__ g_Wie,  // [64,256]
    float* __restrict__ g_out,        // [64,10]
    int T, float dA, float dG)
{
  const int lane = threadIdx.x;              // 0..63
  const int b    = blockIdx.x;
  const int col  = (lane < N_OUT) ? lane : 0;
  const int colO = 64 + col;                 // W1 column inside merged row

  __shared__ __align__(16) float sWieT[N_I * 64 * 4];  // 64 KB  [j][l][g]
  __shared__ __align__(16) float sWeiO[N_E * 80];      // 80 KB  [j][0:64)=Wei, [64:74)=W1
  __shared__ __align__(16) float sZeroRow[256];        // 1 KB zero row

  // ---- one-time staging (single wave; in-order DS + syncthreads below) ----
  {
    // Wie transpose: element Wie[j][e] -> sWieT[(j*64 + (e&63))*4 + (e>>6)]
    const float4* wie4 = (const float4*)g_Wie;         // [64][64] float4 view
    for (int k = lane; k < 64 * 64; k += 64) {
      int j = k >> 6, c4 = k & 63;
      float4 v = wie4[k];
      int e0 = 4 * c4;
      sWieT[(j * 64 + ((e0 + 0) & 63)) * 4 + ((e0 + 0) >> 6)] = v.x;
      sWieT[(j * 64 + ((e0 + 1) & 63)) * 4 + ((e0 + 1) >> 6)] = v.y;
      sWieT[(j * 64 + ((e0 + 2) & 63)) * 4 + ((e0 + 2) >> 6)] = v.z;
      sWieT[(j * 64 + ((e0 + 3) & 63)) * 4 + ((e0 + 3) >> 6)] = v.w;
    }
    const float4* wei4 = (const float4*)g_Wei;         // [256][16] float4 view
    for (int k = lane; k < 256 * 16; k += 64) {
      int r = k >> 4, c4 = k & 15;
      *(float4*)&sWeiO[r * 80 + c4 * 4] = wei4[k];
    }
    for (int k = lane; k < 256 * N_OUT; k += 64) {
      int r = k / N_OUT, o = k - r * N_OUT;
      sWeiO[r * 80 + 64 + o] = fmaxf(g_W1[k], 0.f);
    }
    for (int k = lane; k < 256 * 6; k += 64) {
      int r = k / 6, c = k - r * 6;
      sWeiO[r * 80 + 74 + c] = 0.f;
    }
    for (int k = lane; k < 256; k += 64) sZeroRow[k] = 0.f;
  }
  // detect all-zero W_ee (true for this data; skipping a zero matmul is fp-exact)
  bool wee;
  {
    bool any = false;
    const float4* p = (const float4*)g_Wee;
    for (int k = lane; k < (N_E * N_E) / 4; k += 64) {
      float4 x = p[k];
      any |= (x.x != 0.f) | (x.y != 0.f) | (x.z != 0.f) | (x.w != 0.f);
    }
    wee = (__ballot(any) != 0ull);
  }
  __syncthreads();

  // ---- per-thread state: 4 E neurons (word g, bit lane), I = lane, O replicated ----
  float vE[4], ge[4], gi[4]; int rE[4];
#pragma unroll
  for (int g = 0; g < 4; ++g) { vE[g] = -65.f; ge[g] = 0.f; gi[g] = 0.f; rE[g] = 0; }
  float vI = -65.f, gI = 0.f; int rI = 0;
  float vO = -65.f, gO = 0.f, accO = 0.f; int rO = 0;

  unsigned long long mEw[4] = {0ull, 0ull, 0ull, 0ull};  // s_e(t-1), word g (uniform)
  unsigned long long mI = 0ull;                          // s_i(t-1) (uniform)

  // input + W0 prefetch pipeline (loads for step t issued at t-1)
  float cur = g_in[b * N_IN + lane];
  float n1  = g_in[((T > 1 ? 1 : 0) * BB + b) * N_IN + lane];

  unsigned long long mInC = __ballot(cur != 0.f);
  unsigned long long aRemC = 0ull;
  bool vaC[4] = {false, false, false, false};
  float fw[4][4];
  if (mInC) {
    unsigned long long a = mInC;
    int ja[4];
#pragma unroll
    for (int k = 0; k < 4; ++k) {
      vaC[k] = (a != 0ull); ja[k] = vaC[k] ? (__ffsll(a) - 1) : 0; a &= (a - 1ull);
    }
    aRemC = a;
#pragma unroll
    for (int k = 0; k < 4; ++k)
#pragma unroll
      for (int g = 0; g < 4; ++g)
        fw[k][g] = g_W0[ja[k] * N_E + lane + 64 * g];
  }

  // ================= HOT LOOP (no cross-wave sync anywhere) =================
  for (int t = 0; t < T; ++t) {
    const int tp = (t + 2 < T) ? (t + 2) : (T - 1);
    float n2 = g_in[(tp * BB + b) * N_IN + lane];   // prefetch t+2

    // ---- E gather over s_e(t-1): per-word pEI/kow, ascending, batch 8 ----
    float pEI[4], kow[4];
#pragma unroll
    for (int g = 0; g < 4; ++g) {
      float p = 0.f, ko = 0.f;
      unsigned long long e = mEw[g];
      while (e) {
        const float* qb[8];
#pragma unroll
        for (int k = 0; k < 8; ++k) {
          bool v = (e != 0ull); int j = v ? (__ffsll(e) - 1) : 0; e &= (e - 1ull);
          qb[k] = v ? &sWeiO[(g * 64 + j) * 80] : sZeroRow;
        }
        float fq[8], fr[8];
#pragma unroll
        for (int k = 0; k < 8; ++k) { fq[k] = qb[k][lane]; fr[k] = qb[k][colO]; }
#pragma unroll
        for (int k = 0; k < 8; ++k) p += fq[k];
#pragma unroll
        for (int k = 0; k < 8; ++k) ko += fr[k];
      }
      pEI[g] = p; kow[g] = ko;
    }

    // ---- kie gather over mI(t-1): one b128 per row per lane, batch 8 ----
    float kie[4] = {0.f, 0.f, 0.f, 0.f};
    {
      unsigned long long c = mI;
      while (c) {
        const float* pb[8];
#pragma unroll
        for (int k = 0; k < 8; ++k) {
          bool v = (c != 0ull); int j = v ? (__ffsll(c) - 1) : 0; c &= (c - 1ull);
          pb[k] = v ? &sWieT[j * 256] : sZeroRow;
        }
        float4 f[8];
#pragma unroll
        for (int k = 0; k < 8; ++k) f[k] = *(const float4*)&pb[k][lane * 4];
#pragma unroll
        for (int k = 0; k < 8; ++k) {
          kie[0] += f[k].x; kie[1] += f[k].y; kie[2] += f[k].z; kie[3] += f[k].w;
        }
      }
    }

    // ---- W0 consume (prefetched last iter; ascending) ----
    float kin[4] = {0.f, 0.f, 0.f, 0.f};
    if (mInC) {
#pragma unroll
      for (int k = 0; k < 4; ++k)
#pragma unroll
        for (int g = 0; g < 4; ++g)
          kin[g] += vaC[k] ? fmaxf(fw[k][g], 0.f) : 0.f;
      while (aRemC) {
        int j = __ffsll(aRemC) - 1; aRemC &= (aRemC - 1ull);
#pragma unroll
        for (int g = 0; g < 4; ++g)
          kin[g] += fmaxf(g_W0[j * N_E + lane + 64 * g], 0.f);
      }
    }

    // ---- kee gather (fallback only; absolute ascending j, one at a time) ----
    float kee[4] = {0.f, 0.f, 0.f, 0.f};
    if (wee) {
      unsigned long long m0 = mEw[0], m1 = mEw[1], m2 = mEw[2], m3 = mEw[3];
      while (m0 | m1 | m2 | m3) {
        int idx = 0;
        if (m0)      { idx = __ffsll(m0) - 1;       m0 &= (m0 - 1ull); }
        else if (m1) { idx = 64 + __ffsll(m1) - 1;  m1 &= (m1 - 1ull); }
        else if (m2) { idx = 128 + __ffsll(m2) - 1; m2 &= (m2 - 1ull); }
        else         { idx = 192 + __ffsll(m3) - 1; m3 &= (m3 - 1ull); }
#pragma unroll
        for (int g = 0; g < 4; ++g)
          kee[g] += g_Wee[idx * N_E + lane + 64 * g];
      }
    }

    // ---- E LIF x4 (COBA, C_m=1, g_L=0.05, ref=12) -> mEw(t) ----
#pragma unroll
    for (int g = 0; g < 4; ++g) {
      ge[g] = ((ge[g] + kin[g]) + kee[g]) * dA;   // kee==0.0f exact no-op when !wee
      gi[g] = (gi[g] + kie[g]) * dG;
      float t2 = ge[g] * (0.f - vE[g]);
      float t3 = gi[g] * (-80.f - vE[g]);
      float Itot = t2 + t3;
      float dv = 0.25f * ((-0.05f) * (vE[g] - (-65.f)) + Itot);
      dv = dv * 0.0125f + dv * 0.9875f;           // _scale_grad forward (not fp-identity)
      vE[g] = fmaxf(vE[g] + dv, -200.f);
      rE[g] = rE[g] - 1; if (rE[g] < 0) rE[g] = 0;
      bool can = (rE[g] == 0);
      bool sE = ((vE[g] - (-50.f)) >= 0.f) && can;
      vE[g] = (sE || !can) ? -65.f : vE[g];
      rE[g] = sE ? 12 : rE[g];
      mEw[g] = __ballot(sE);
    }

    // ---- W0 prefetch for t+1 ----
    mInC = __ballot(n1 != 0.f);
    aRemC = 0ull;
    vaC[0] = vaC[1] = vaC[2] = vaC[3] = false;
    if (mInC) {
      unsigned long long a = mInC;
      int ja[4];
#pragma unroll
      for (int k = 0; k < 4; ++k) {
        vaC[k] = (a != 0ull); ja[k] = vaC[k] ? (__ffsll(a) - 1) : 0; a &= (a - 1ull);
      }
      aRemC = a;
#pragma unroll
      for (int k = 0; k < 4; ++k)
#pragma unroll
        for (int g = 0; g < 4; ++g)
          fw[k][g] = g_W0[ja[k] * N_E + lane + 64 * g];
    }

    // ---- I LIF (lane = I neuron; C_m=0.5, g_L=0.1, ref=6) -> mI(t) ----
    {
      float p = ((pEI[0] + pEI[1]) + pEI[2]) + pEI[3];
      gI = (gI + p) * dA;
      float Ii = gI * (0.f - vI);
      float dvi = 0.5f * ((-0.1f) * (vI - (-65.f)) + Ii);
      dvi = dvi * 0.0125f + dvi * 0.9875f;
      vI = fmaxf(vI + dvi, -200.f);
      rI = rI - 1; if (rI < 0) rI = 0;
      bool canI = (rI == 0);
      bool sI = ((vI - (-50.f)) >= 0.f) && canI;
      vI = (sI || !canI) ? -65.f : vI;
      rI = sI ? 6 : rI;
      mI = __ballot(sI);
    }

    // ---- O LIF (replicated, step t-1; iter 0 = exact fp no-op) ----
    {
      float ko = ((kow[0] + kow[1]) + kow[2]) + kow[3];
      gO = (gO + ko) * dA;
      float Io = gO * (0.f - vO);
      float dvo = 0.25f * ((-0.05f) * (vO - (-65.f)) + Io);
      dvo = dvo * 0.0125f + dvo * 0.9875f;
      vO = fmaxf(vO + dvo, -200.f);
      rO = rO - 1; if (rO < 0) rO = 0;
      bool canO = (rO == 0);
      bool sO = ((vO - (-50.f)) >= 0.f) && canO;
      vO = (sO || !canO) ? -65.f : vO;
      rO = sO ? 12 : rO;
      accO += sO ? 1.f : 0.f;
    }

    cur = n1; n1 = n2;
  }

  // ---- drain: O step T-1 over s_e(T-1) (all words in-register) ----
  {
    float kd[4];
#pragma unroll
    for (int g = 0; g < 4; ++g) {
      float k2 = 0.f;
      unsigned long long e = mEw[g];
      while (e) {
        const float* rb[8];
#pragma unroll
        for (int k = 0; k < 8; ++k) {
          bool v = (e != 0ull); int j = v ? (__ffsll(e) - 1) : 0; e &= (e - 1ull);
          rb[k] = v ? &sWeiO[(g * 64 + j) * 80] : sZeroRow;
        }
        float fr[8];
#pragma unroll
        for (int k = 0; k < 8; ++k) fr[k] = rb[k][colO];
#pragma unroll
        for (int k = 0; k < 8; ++k) k2 += fr[k];
      }
      kd[g] = k2;
    }
    float ko = ((kd[0] + kd[1]) + kd[2]) + kd[3];
    gO = (gO + ko) * dA;
    float Io = gO * (0.f - vO);
    float dvo = 0.25f * ((-0.05f) * (vO - (-65.f)) + Io);
    dvo = dvo * 0.0125f + dvo * 0.9875f;
    vO = fmaxf(vO + dvo, -200.f);
    rO = rO - 1; if (rO < 0) rO = 0;
    bool canO = (rO == 0);
    bool sO = ((vO - (-50.f)) >= 0.f) && canO;
    accO += sO ? 1.f : 0.f;
  }

  if (lane < N_OUT) g_out[b * N_OUT + lane] = accO;
}

extern "C" void kernel_launch(void* const* d_in, const int* in_sizes, int n_in,
                              void* d_out, int out_size, void* d_ws, size_t ws_size,
                              hipStream_t stream) {
  const float* g_in  = (const float*)d_in[0];
  const float* g_W0  = (const float*)d_in[1];
  const float* g_W1  = (const float*)d_in[2];
  const float* g_Wee = (const float*)d_in[3];
  const float* g_Wei = (const float*)d_in[4];
  const float* g_Wie = (const float*)d_in[5];
  float* out = (float*)d_out;
  int T = in_sizes[0] / (BB * N_IN);
  float dA = (float)exp(-0.25 / 2.0);   // tau_ampa = 2.0
  float dG = (float)exp(-0.25 / 9.0);   // tau_gaba = 9.0
  ping_kernel<<<dim3(BB), dim3(64), 0, stream>>>(g_in, g_W0, g_W1, g_Wee, g_Wei, g_Wie, out, T, dA, dG);
}

// Round 3
// 4761.793 us; speedup vs baseline: 1.7570x; 1.7570x over previous
//
#include <hip/hip_runtime.h>
#include <math.h>

#pragma clang fp contract(off)

#define BB 64      // batch
#define N_IN 64
#define N_E 256
#define N_I 64
#define N_OUT 10

__device__ inline unsigned long long rfl64(unsigned long long x) {
  unsigned int lo = __builtin_amdgcn_readfirstlane((unsigned int)x);
  unsigned int hi = __builtin_amdgcn_readfirstlane((unsigned int)(x >> 32));
  return (((unsigned long long)hi) << 32) | (unsigned long long)lo;
}

// r15: PRODUCER/CONSUMER pipeline. Waves 0-3 = E-side (old 4-wave layout:
// thread tid<256 owns E neuron tid; wave w's ballot = E-word w). Wave 4 =
// I/O-side consumer. Key property: mI(t) is needed by producers only at step
// t+1 (kie gather), and partials(t) are needed only by wave4 -> the old
// every-step all-wave poll (which stalled every wave on the slowest wave)
// is replaced by a 1-step-slack handoff. Producers' steady-state hot path
// has NO polls and NO barriers.
//  * partials publish: sPK/sKoT writes, compiler barrier, tag write (DS ops
//    of one wave complete in order -- the verified r13 property).
//  * mI publish (wave4): data u64 write, compiler barrier, volatile tag.
//  * mI early-probe (producers): volatile tag read THEN volatile data read
//    issued at step start; checked after gather+publish. tag match => data
//    write (which preceded the tag write) completed before our tag read,
//    and our data read completes after our tag read (in-order) => fresh.
//    Miss => poll tag, re-read data (read-after-matched-tag, safe).
//  * slot safety (depth 2): a wave publishing partials(t) finished step t-1
//    and thus checked mI(t-2) => wave4 published mI(t-2) => wave4 consumed
//    partials(t-2) from the slot being overwritten. Symmetric for sMI.
// All float sequences / gather orders / reduction association identical to
// the verified 4770us kernel (batch-8 zero-row padding adds exact +0.0f).
__global__ __launch_bounds__(320, 1) void ping_kernel(
    const float* __restrict__ g_in,   // [T,64,64]
    const float* __restrict__ g_W0,   // [64,256]  clamp >=0 at use
    const float* __restrict__ g_W1,   // [256,10]  clamp >=0 at stage
    const float* __restrict__ g_Wee,  // [256,256]
    const float* __restrict__ g_Wei,  // [256,64]
    const float* __restrict__ g_Wie,  // [64,256]
    float* __restrict__ g_out,        // [64,10]
    int T, float dA, float dG)
{
  const int tid  = threadIdx.x;              // 0..319
  const int lane = tid & 63;
  const int wav  = tid >> 6;                 // 0..4
  const int b    = blockIdx.x;
  const int col  = (lane < N_OUT) ? lane : 0;
  const int colO = 64 + col;                 // W1 column inside merged row
  const int base64 = wav * 64;               // valid for wav<4

  __shared__ float sWie[N_I * N_E];          // 64 KB  [j][e]
  __shared__ float sWeiO[N_E * 80];          // 80 KB  [j][0:64)=Wei, [64:74)=W1
  __shared__ float sZeroRow[256];            // 1 KB zero row
  __shared__ __align__(16) float sPK[2][64][4];   // E->I partials [slot][lane][wave]
  __shared__ __align__(16) float sKoT[2][16][4];  // E->O partials [slot][col][wave]
  __shared__ __align__(16) unsigned sTag[2][4];   // partial tags (16B quads)
  __shared__ __align__(8) unsigned long long sMI[2];  // mI value per slot
  __shared__ unsigned sMITag[2];                      // mI tag per slot
  __shared__ unsigned long long sME[2][4];   // E masks (wee fallback only)
  __shared__ int sWee;

  // ---- one-time staging (320 threads) ----
  {
    const float4* s0 = (const float4*)g_Wie; float4* d0 = (float4*)sWie;
    for (int k = tid; k < (N_I * N_E) / 4; k += 320) d0[k] = s0[k];
    const float4* wei4 = (const float4*)g_Wei;         // [256][16] float4 view
    for (int k = tid; k < 256 * 16; k += 320) {
      int r = k >> 4, c4 = k & 15;
      *(float4*)&sWeiO[r * 80 + c4 * 4] = wei4[k];
    }
    for (int k = tid; k < 256 * N_OUT; k += 320) {
      int r = k / N_OUT, o = k - r * N_OUT;
      sWeiO[r * 80 + 64 + o] = fmaxf(g_W1[k], 0.f);
    }
    for (int k = tid; k < 256 * 6; k += 320) {
      int r = k / 6, c = k - r * 6;
      sWeiO[r * 80 + 74 + c] = 0.f;
    }
    for (int k = tid; k < 256; k += 320) sZeroRow[k] = 0.f;
  }
  if (tid < 8) sTag[tid >> 2][tid & 3] = 0u;
  if (tid < 8) sME[tid >> 2][tid & 3] = 0ull;
  if (tid < 2) { sMI[tid] = 0ull; sMITag[tid] = 0u; }
  if (tid == 0) sWee = 0;
  __syncthreads();
  // detect all-zero W_ee (true for this data; skipping a zero matmul is fp-exact)
  {
    bool any = false;
    const float4* p = (const float4*)g_Wee;
    for (int k = tid; k < (N_E * N_E) / 4; k += 320) {
      float4 x = p[k];
      any |= (x.x != 0.f) | (x.y != 0.f) | (x.z != 0.f) | (x.w != 0.f);
    }
    if (any) sWee = 1;   // benign race: all writers store 1
  }
  __syncthreads();
  const int wee = sWee;

  // ---- per-role state (function scope so the drains can see it) ----
  float vE = -65.f, ge = 0.f, gi = 0.f; int rE = 0;     // E neuron = tid (wav<4)
  unsigned long long mE = 0ull;                          // own E word, s_e(t-1)
  float vI = -65.f, gI = 0.f; int rI = 0;               // I neuron = lane
  unsigned long long mI = 0ull;                          // s_i(t-1)
  float vO = -65.f, gO = 0.f, accO = 0.f; int rO = 0;   // output (replicated)

  // input + W0 prefetch pipeline (producers only)
  float cur = 0.f, n1 = 0.f;
  unsigned long long mInC = 0ull, aRemC = 0ull;
  bool vaC[4] = {false, false, false, false};
  float fwC[4];
  if (wav < 4) {
    cur = g_in[b * N_IN + lane];
    n1  = g_in[((T > 1 ? 1 : 0) * BB + b) * N_IN + lane];
    mInC = __ballot(cur != 0.f);
    if (mInC) {
      unsigned long long a = mInC;
      int ja[4];
#pragma unroll
      for (int k = 0; k < 4; ++k) {
        vaC[k] = (a != 0ull); ja[k] = vaC[k] ? (__ffsll(a) - 1) : 0; a &= (a - 1ull);
      }
      aRemC = a;
#pragma unroll
      for (int k = 0; k < 4; ++k) fwC[k] = g_W0[ja[k] * N_E + tid];
    }
  }

  if (wav < 4) {
    if (!wee) {
      // ================= PRODUCER HOT LOOP (no polls in steady state) =================
      for (int t = 0; t < T; ++t) {
        const int slot = t & 1;
        const int slotP = (t + 1) & 1;       // slot holding mI(t-1)
        // early probe for mI(t-1): tag THEN data (both volatile, in-order DS)
        unsigned tgP = *((volatile unsigned*)&sMITag[slotP]);
        unsigned long long mdP = *((volatile unsigned long long*)&sMI[slotP]);

        const int tp = (t + 2 < T) ? (t + 2) : (T - 1);
        float n2 = g_in[(tp * BB + b) * N_IN + lane];   // prefetch t+2

        // ---- E gather over own word of s_e(t-1): pEI/kow, ascending, batch 8 ----
        float pEI = 0.f, kow = 0.f;
        {
          unsigned long long e = mE;
          while (e) {
            const float* qb[8];
#pragma unroll
            for (int k = 0; k < 8; ++k) {
              bool v = (e != 0ull); int j = v ? (__ffsll(e) - 1) : 0; e &= (e - 1ull);
              qb[k] = v ? &sWeiO[(base64 + j) * 80] : sZeroRow;
            }
            float fq[8], fr[8];
#pragma unroll
            for (int k = 0; k < 8; ++k) { fq[k] = qb[k][lane]; fr[k] = qb[k][colO]; }
#pragma unroll
            for (int k = 0; k < 8; ++k) pEI += fq[k];
#pragma unroll
            for (int k = 0; k < 8; ++k) kow += fr[k];
          }
        }

        // ---- publish partials, then tag (DS in-order; compiler barrier only) ----
        sPK[slot][lane][wav] = pEI;
        if (lane < 16) sKoT[slot][lane][wav] = kow;
        asm volatile("" ::: "memory");
        if (lane == 0) *((volatile unsigned*)&sTag[slot][wav]) = (unsigned)(t + 1);

        // ---- resolve mI(t-1): probe hit expected (wave4 has ~1 step slack) ----
        unsigned long long mIc;
        if (tgP == (unsigned)t) {
          mIc = mdP;
        } else {
          volatile unsigned* vt = (volatile unsigned*)&sMITag[slotP];
          while (*vt != (unsigned)t) {}
          asm volatile("" ::: "memory");
          mIc = *((volatile unsigned long long*)&sMI[slotP]);
        }

        // ---- kie gather over mI(t-1) ----
        float kie = 0.f;
        {
          unsigned long long c = mIc;
          while (c) {
            const float* pb[8];
#pragma unroll
            for (int k = 0; k < 8; ++k) {
              bool v = (c != 0ull); int j = v ? (__ffsll(c) - 1) : 0; c &= (c - 1ull);
              pb[k] = v ? &sWie[j * N_E] : sZeroRow;
            }
            float fI[8];
#pragma unroll
            for (int k = 0; k < 8; ++k) fI[k] = pb[k][tid];
#pragma unroll
            for (int k = 0; k < 8; ++k) kie += fI[k];
          }
        }

        // ---- W0 consume (prefetched last iter; ascending) ----
        float kin = 0.f;
        if (mInC) {
#pragma unroll
          for (int k = 0; k < 4; ++k) kin += vaC[k] ? fmaxf(fwC[k], 0.f) : 0.f;
          while (aRemC) {
            int j = __ffsll(aRemC) - 1; aRemC &= (aRemC - 1ull);
            kin += fmaxf(g_W0[j * N_E + tid], 0.f);
          }
        }

        // ---- E LIF (COBA, C_m=1, g_L=0.05, ref=12) -> mE(t) ----
        ge = (ge + kin) * dA;           // kee == 0 exactly (wee false)
        gi = (gi + kie) * dG;
        {
          float t2 = ge * (0.f - vE);
          float t3 = gi * (-80.f - vE);
          float Itot = t2 + t3;
          float dv = 0.25f * ((-0.05f) * (vE - (-65.f)) + Itot);
          dv = dv * 0.0125f + dv * 0.9875f;      // _scale_grad forward (not fp-identity)
          vE = fmaxf(vE + dv, -200.f);
          rE = rE - 1; if (rE < 0) rE = 0;
          bool can = (rE == 0);
          bool sE = ((vE - (-50.f)) >= 0.f) && can;
          vE = (sE || !can) ? -65.f : vE;
          rE = sE ? 12 : rE;
          mE = __ballot(sE);
        }

        // ---- W0 prefetch for t+1 ----
        mInC = __ballot(n1 != 0.f);
        aRemC = 0ull;
        vaC[0] = vaC[1] = vaC[2] = vaC[3] = false;
        if (mInC) {
          unsigned long long a = mInC;
          int ja[4];
#pragma unroll
          for (int k = 0; k < 4; ++k) {
            vaC[k] = (a != 0ull); ja[k] = vaC[k] ? (__ffsll(a) - 1) : 0; a &= (a - 1ull);
          }
          aRemC = a;
#pragma unroll
          for (int k = 0; k < 4; ++k) fwC[k] = g_W0[ja[k] * N_E + tid];
        }

        cur = n1; n1 = n2;
      }
    } else {
      // ============ FALLBACK (wee != 0): old 4-wave barrier loop verbatim ============
      unsigned long long we0 = 0ull, we1 = 0ull, we2 = 0ull, we3 = 0ull;
      for (int t = 0; t < T; ++t) {
        const int slot = t & 1;
        const int tp = (t + 2 < T) ? (t + 2) : (T - 1);
        float n2 = g_in[(tp * BB + b) * N_IN + lane];

        float pEI = 0.f, kow = 0.f;
        {
          unsigned long long e = mE;
          while (e) {
            const float* qb[4];
#pragma unroll
            for (int k = 0; k < 4; ++k) {
              bool v = (e != 0ull); int j = v ? (__ffsll(e) - 1) : 0; e &= (e - 1ull);
              qb[k] = v ? &sWeiO[(base64 + j) * 80] : sZeroRow;
            }
            float fq[4], fr[4];
#pragma unroll
            for (int k = 0; k < 4; ++k) { fq[k] = qb[k][lane]; fr[k] = qb[k][colO]; }
#pragma unroll
            for (int k = 0; k < 4; ++k) pEI += fq[k];
#pragma unroll
            for (int k = 0; k < 4; ++k) kow += fr[k];
          }
        }
        sPK[slot][lane][wav] = pEI;
        if (lane < 16) sKoT[slot][lane][wav] = kow;
        asm volatile("s_waitcnt lgkmcnt(0)" ::: "memory");
        if (lane == 0) *((volatile unsigned*)&sTag[slot][wav]) = (unsigned)(t + 1);

        float kie = 0.f;
        {
          unsigned long long c = mI;
          while (c) {
            const float* pb[8];
#pragma unroll
            for (int k = 0; k < 8; ++k) {
              bool v = (c != 0ull); int j = v ? (__ffsll(c) - 1) : 0; c &= (c - 1ull);
              pb[k] = v ? &sWie[j * N_E] : sZeroRow;
            }
            float fI[8];
#pragma unroll
            for (int k = 0; k < 8; ++k) fI[k] = pb[k][tid];
#pragma unroll
            for (int k = 0; k < 8; ++k) kie += fI[k];
          }
        }

        float kin = 0.f;
        if (mInC) {
#pragma unroll
          for (int k = 0; k < 4; ++k) kin += vaC[k] ? fmaxf(fwC[k], 0.f) : 0.f;
          while (aRemC) {
            int j = __ffsll(aRemC) - 1; aRemC &= (aRemC - 1ull);
            kin += fmaxf(g_W0[j * N_E + tid], 0.f);
          }
        }

        float kee = 0.f;
        {
          unsigned long long m0 = we0, m1 = we1, m2 = we2, m3 = we3;
          while (m0 | m1 | m2 | m3) {
            int idx = 0;
            if (m0)      { idx = __ffsll(m0) - 1;       m0 &= (m0 - 1ull); }
            else if (m1) { idx = 64 + __ffsll(m1) - 1;  m1 &= (m1 - 1ull); }
            else if (m2) { idx = 128 + __ffsll(m2) - 1; m2 &= (m2 - 1ull); }
            else         { idx = 192 + __ffsll(m3) - 1; m3 &= (m3 - 1ull); }
            kee += g_Wee[idx * N_E + tid];
          }
        }

        ge = ((ge + kin) + kee) * dA;
        gi = (gi + kie) * dG;
        {
          float t2 = ge * (0.f - vE);
          float t3 = gi * (-80.f - vE);
          float Itot = t2 + t3;
          float dv = 0.25f * ((-0.05f) * (vE - (-65.f)) + Itot);
          dv = dv * 0.0125f + dv * 0.9875f;
          vE = fmaxf(vE + dv, -200.f);
          rE = rE - 1; if (rE < 0) rE = 0;
          bool can = (rE == 0);
          bool sE = ((vE - (-50.f)) >= 0.f) && can;
          vE = (sE || !can) ? -65.f : vE;
          rE = sE ? 12 : rE;
          unsigned long long fresh = __ballot(sE);
          if (lane == 0) sME[slot][wav] = fresh;
          mE = fresh;
        }

        mInC = __ballot(n1 != 0.f);
        aRemC = 0ull;
        vaC[0] = vaC[1] = vaC[2] = vaC[3] = false;
        if (mInC) {
          unsigned long long a = mInC;
          int ja[4];
#pragma unroll
          for (int k = 0; k < 4; ++k) {
            vaC[k] = (a != 0ull); ja[k] = vaC[k] ? (__ffsll(a) - 1) : 0; a &= (a - 1ull);
          }
          aRemC = a;
#pragma unroll
          for (int k = 0; k < 4; ++k) fwC[k] = g_W0[ja[k] * N_E + tid];
        }

        {
          const unsigned want = (unsigned)(t + 1);
          const unsigned long long want2 = (((unsigned long long)want) << 32) | want;
          volatile unsigned long long* vt = (volatile unsigned long long*)&sTag[slot][0];
          while (true) {
            unsigned long long a0 = vt[0], a1 = vt[1];
            if (((a0 ^ want2) | (a1 ^ want2)) == 0ull) break;
          }
          asm volatile("" ::: "memory");
        }

        float4 P = *(const float4*)&sPK[slot][lane][0];
        float4 K = *(const float4*)&sKoT[slot][col][0];

        {
          float p = ((P.x + P.y) + P.z) + P.w;
          gI = (gI + p) * dA;
          float Ii = gI * (0.f - vI);
          float dvi = 0.5f * ((-0.1f) * (vI - (-65.f)) + Ii);
          dvi = dvi * 0.0125f + dvi * 0.9875f;
          vI = fmaxf(vI + dvi, -200.f);
          rI = rI - 1; if (rI < 0) rI = 0;
          bool canI = (rI == 0);
          bool sI = ((vI - (-50.f)) >= 0.f) && canI;
          vI = (sI || !canI) ? -65.f : vI;
          rI = sI ? 6 : rI;
          mI = __ballot(sI);
        }

        {
          float ko = ((K.x + K.y) + K.z) + K.w;
          gO = (gO + ko) * dA;
          float Io = gO * (0.f - vO);
          float dvo = 0.25f * ((-0.05f) * (vO - (-65.f)) + Io);
          dvo = dvo * 0.0125f + dvo * 0.9875f;
          vO = fmaxf(vO + dvo, -200.f);
          rO = rO - 1; if (rO < 0) rO = 0;
          bool canO = (rO == 0);
          bool sO = ((vO - (-50.f)) >= 0.f) && canO;
          vO = (sO || !canO) ? -65.f : vO;
          rO = sO ? 12 : rO;
          accO += sO ? 1.f : 0.f;
        }

        __syncthreads();   // fallback path: make sME visible
        we0 = rfl64(sME[slot][0]); we1 = rfl64(sME[slot][1]);
        we2 = rfl64(sME[slot][2]); we3 = rfl64(sME[slot][3]);

        cur = n1; n1 = n2;
      }
    }
  } else {
    // ======================= WAVE 4: I/O CONSUMER =======================
    if (!wee) {
      for (int t = 0; t < T; ++t) {
        const int slot = t & 1;
        // poll the 4 partial tags (slack absorbs producer skew)
        {
          const unsigned want = (unsigned)(t + 1);
          const unsigned long long want2 = (((unsigned long long)want) << 32) | want;
          volatile unsigned long long* vt = (volatile unsigned long long*)&sTag[slot][0];
          while (true) {
            unsigned long long a0 = vt[0], a1 = vt[1];
            if (((a0 ^ want2) | (a1 ^ want2)) == 0ull) break;
          }
          asm volatile("" ::: "memory");
        }
        float4 P = *(const float4*)&sPK[slot][lane][0];
        float4 K = *(const float4*)&sKoT[slot][col][0];

        unsigned long long mIv;
        {
          float p = ((P.x + P.y) + P.z) + P.w;
          gI = (gI + p) * dA;
          float Ii = gI * (0.f - vI);
          float dvi = 0.5f * ((-0.1f) * (vI - (-65.f)) + Ii);
          dvi = dvi * 0.0125f + dvi * 0.9875f;
          vI = fmaxf(vI + dvi, -200.f);
          rI = rI - 1; if (rI < 0) rI = 0;
          bool canI = (rI == 0);
          bool sI = ((vI - (-50.f)) >= 0.f) && canI;
          vI = (sI || !canI) ? -65.f : vI;
          rI = sI ? 6 : rI;
          mIv = __ballot(sI);
        }

        {
          float ko = ((K.x + K.y) + K.z) + K.w;
          gO = (gO + ko) * dA;
          float Io = gO * (0.f - vO);
          float dvo = 0.25f * ((-0.05f) * (vO - (-65.f)) + Io);
          dvo = dvo * 0.0125f + dvo * 0.9875f;
          vO = fmaxf(vO + dvo, -200.f);
          rO = rO - 1; if (rO < 0) rO = 0;
          bool canO = (rO == 0);
          bool sO = ((vO - (-50.f)) >= 0.f) && canO;
          vO = (sO || !canO) ? -65.f : vO;
          rO = sO ? 12 : rO;
          accO += sO ? 1.f : 0.f;
        }

        // publish mI(t): data, compiler barrier, tag (DS in-order)
        if (lane == 0) {
          sMI[slot] = mIv;
          asm volatile("" ::: "memory");
          *((volatile unsigned*)&sMITag[slot]) = (unsigned)(t + 1);
        }
      }
    } else {
      for (int t = 0; t < T; ++t) __syncthreads();   // match fallback barrier count
    }
  }

  // ---- drain: O step T-1 over s_e(T-1) ----
  if (!wee) {
    float kd = 0.f;
    if (wav < 4) {
      unsigned long long e = mE;
      while (e) {
        const float* rb[8];
#pragma unroll
        for (int k = 0; k < 8; ++k) {
          bool v = (e != 0ull); int j = v ? (__ffsll(e) - 1) : 0; e &= (e - 1ull);
          rb[k] = v ? &sWeiO[(base64 + j) * 80] : sZeroRow;
        }
        float fr[8];
#pragma unroll
        for (int k = 0; k < 8; ++k) fr[k] = rb[k][colO];
#pragma unroll
        for (int k = 0; k < 8; ++k) kd += fr[k];
      }
    }
    __syncthreads();                 // wave4 done with all slots
    if (wav < 4 && lane < 16) sKoT[0][lane][wav] = kd;
    __syncthreads();
    if (wav == 4) {
      float4 K = *(const float4*)&sKoT[0][col][0];
      float ko = ((K.x + K.y) + K.z) + K.w;
      gO = (gO + ko) * dA;
      float Io = gO * (0.f - vO);
      float dvo = 0.25f * ((-0.05f) * (vO - (-65.f)) + Io);
      dvo = dvo * 0.0125f + dvo * 0.9875f;
      vO = fmaxf(vO + dvo, -200.f);
      rO = rO - 1; if (rO < 0) rO = 0;
      bool canO = (rO == 0);
      bool sO = ((vO - (-50.f)) >= 0.f) && canO;
      accO += sO ? 1.f : 0.f;
      if (lane < N_OUT) g_out[b * N_OUT + lane] = accO;
    }
  } else {
    float kd = 0.f;
    if (wav < 4) {
      unsigned long long e = mE;
      while (e) {
        const float* rb[4];
#pragma unroll
        for (int k = 0; k < 4; ++k) {
          bool v = (e != 0ull); int j = v ? (__ffsll(e) - 1) : 0; e &= (e - 1ull);
          rb[k] = v ? &sWeiO[(base64 + j) * 80] : sZeroRow;
        }
        float fr[4];
#pragma unroll
        for (int k = 0; k < 4; ++k) fr[k] = rb[k][colO];
#pragma unroll
        for (int k = 0; k < 4; ++k) kd += fr[k];
      }
    }
    __syncthreads();
    if (wav < 4 && lane < 16) sKoT[0][lane][wav] = kd;
    __syncthreads();
    if (wav < 4) {
      float4 K = *(const float4*)&sKoT[0][col][0];
      float ko = ((K.x + K.y) + K.z) + K.w;
      gO = (gO + ko) * dA;
      float Io = gO * (0.f - vO);
      float dvo = 0.25f * ((-0.05f) * (vO - (-65.f)) + Io);
      dvo = dvo * 0.0125f + dvo * 0.9875f;
      vO = fmaxf(vO + dvo, -200.f);
      rO = rO - 1; if (rO < 0) rO = 0;
      bool canO = (rO == 0);
      bool sO = ((vO - (-50.f)) >= 0.f) && canO;
      accO += sO ? 1.f : 0.f;
      if (wav == 0 && lane < N_OUT) g_out[b * N_OUT + lane] = accO;
    }
  }
}

extern "C" void kernel_launch(void* const* d_in, const int* in_sizes, int n_in,
                              void* d_out, int out_size, void* d_ws, size_t ws_size,
                              hipStream_t stream) {
  const float* g_in  = (const float*)d_in[0];
  const float* g_W0  = (const float*)d_in[1];
  const float* g_W1  = (const float*)d_in[2];
  const float* g_Wee = (const float*)d_in[3];
  const float* g_Wei = (const float*)d_in[4];
  const float* g_Wie = (const float*)d_in[5];
  float* out = (float*)d_out;
  int T = in_sizes[0] / (BB * N_IN);
  float dA = (float)exp(-0.25 / 2.0);   // tau_ampa = 2.0
  float dG = (float)exp(-0.25 / 9.0);   // tau_gaba = 9.0
  ping_kernel<<<dim3(BB), dim3(320), 0, stream>>>(g_in, g_W0, g_W1, g_Wee, g_Wei, g_Wie, out, T, dA, dG);
}